// Round 1
// baseline (7059.966 us; speedup 1.0000x reference)
//
#include <hip/hip_runtime.h>

#define VOCAB 5000
#define EMB   128
#define HID   512
#define STK   128
#define BSZ   128
#define TLEN  128
#define KZ    768   // EMB + STK + HID
#define NG    2048  // 4*HID

// ---------------- prologue: build combined, gate-interleaved weight matrix ----------------
// Wc row (4j+g) = [ W_ih[g*HID+j][0:256] | W_hh[g*HID+j][0:512] ]   (g: 0=i,1=f,2=g,3=o)
// bc[4j+g] = b_ih[g*HID+j] + b_hh[g*HID+j]
__global__ __launch_bounds__(256) void build_wc(
    const float* __restrict__ W_ih, const float* __restrict__ W_hh,
    const float* __restrict__ b_ih, const float* __restrict__ b_hh,
    float* __restrict__ Wc, float* __restrict__ bc) {
  int idx = blockIdx.x * 256 + threadIdx.x;
  if (idx >= NG * KZ) return;
  int rd = idx / KZ, col = idx % KZ;
  int j = rd >> 2, g = rd & 3;
  int rs = g * HID + j;
  float v = (col < EMB + STK) ? W_ih[rs * (EMB + STK) + col]
                              : W_hh[rs * HID + (col - (EMB + STK))];
  Wc[idx] = v;
  if (col == 0) bc[rd] = b_ih[rs] + b_hh[rs];
}

// ---------------- prologue: init state (ws is poisoned 0xAA before every call) ----------------
// z0[b] = [ emb[x[0,b]] , r0=1.0 , h0=0 ];  c=0;  s=0;  accb=0
__global__ __launch_bounds__(256) void init_state(
    const int* __restrict__ x, const float* __restrict__ emb,
    float* __restrict__ z0, float* __restrict__ c,
    float* __restrict__ s, float* __restrict__ accb) {
  int idx = blockIdx.x * 256 + threadIdx.x;
  if (idx < BSZ * KZ) {
    int b = idx / KZ, d = idx % KZ;
    float v;
    if (d < EMB)            v = emb[x[b] * EMB + d];
    else if (d < EMB + STK) v = 1.0f;
    else                    v = 0.0f;
    z0[idx] = v;
    return;
  }
  idx -= BSZ * KZ;
  if (idx < BSZ * HID) { c[idx] = 0.f; return; }
  idx -= BSZ * HID;
  if (idx < BSZ * TLEN) { s[idx] = 0.f; return; }
  idx -= BSZ * TLEN;
  if (idx < BSZ) accb[idx] = 0.f;
}

// ---------------- per-step: gates GEMM fused with LSTM cell ----------------
// grid(64 colgroups, 4 batchgroups), 256 thr. Tile [32 b x 32 gate-cols] = 8 units.
// thread -> (b_local = tid>>3, unit_local = tid&7), owns the 4 gates of one unit for one b.
__global__ __launch_bounds__(256) void gates_cell(
    const float* __restrict__ zin, float* __restrict__ znext,
    const float* __restrict__ Wc, const float* __restrict__ bc,
    float* __restrict__ c) {
  __shared__ float ZT[32][65];   // padded: bank-conflict-free broadcast reads
  __shared__ float WTt[64][36];  // transposed W tile, 16B-aligned float4 rows
  const int cg = blockIdx.x;
  const int bg = blockIdx.y;
  const int tid = threadIdx.x;
  const int bl = tid >> 3;
  const int ul = tid & 7;
  const int r  = tid >> 3;        // load row 0..31
  const int ci = (tid & 7) * 8;   // load col base 0..56
  float a0 = 0.f, a1 = 0.f, a2 = 0.f, a3 = 0.f;
  for (int kc = 0; kc < KZ; kc += 64) {
    float4 za = *(const float4*)&zin[(bg * 32 + r) * KZ + kc + ci];
    float4 zb = *(const float4*)&zin[(bg * 32 + r) * KZ + kc + ci + 4];
    float4 wa = *(const float4*)&Wc[(cg * 32 + r) * KZ + kc + ci];
    float4 wb = *(const float4*)&Wc[(cg * 32 + r) * KZ + kc + ci + 4];
    ZT[r][ci + 0] = za.x; ZT[r][ci + 1] = za.y; ZT[r][ci + 2] = za.z; ZT[r][ci + 3] = za.w;
    ZT[r][ci + 4] = zb.x; ZT[r][ci + 5] = zb.y; ZT[r][ci + 6] = zb.z; ZT[r][ci + 7] = zb.w;
    WTt[ci + 0][r] = wa.x; WTt[ci + 1][r] = wa.y; WTt[ci + 2][r] = wa.z; WTt[ci + 3][r] = wa.w;
    WTt[ci + 4][r] = wb.x; WTt[ci + 5][r] = wb.y; WTt[ci + 6][r] = wb.z; WTt[ci + 7][r] = wb.w;
    __syncthreads();
#pragma unroll 16
    for (int k = 0; k < 64; ++k) {
      float zv = ZT[bl][k];
      float4 wv = *(const float4*)&WTt[k][ul * 4];
      a0 = fmaf(zv, wv.x, a0);
      a1 = fmaf(zv, wv.y, a1);
      a2 = fmaf(zv, wv.z, a2);
      a3 = fmaf(zv, wv.w, a3);
    }
    __syncthreads();
  }
  const int rbase = cg * 32 + ul * 4;  // global Wc row of gate i
  const int j = cg * 8 + ul;           // global hidden unit
  const int b = bg * 32 + bl;
  float gi = a0 + bc[rbase + 0];
  float gf = a1 + bc[rbase + 1];
  float gg = a2 + bc[rbase + 2];
  float go = a3 + bc[rbase + 3];
  float si = 1.f / (1.f + expf(-gi));
  float sf = 1.f / (1.f + expf(-gf));
  float tg = tanhf(gg);
  float so = 1.f / (1.f + expf(-go));
  float cn = sf * c[b * HID + j] + si * tg;
  c[b * HID + j] = cn;
  znext[b * KZ + (EMB + STK) + j] = so * tanhf(cn);  // h into next z
}

// ---------------- per-step: pop/push/vals + continuous stack + read r + next xt ----------------
// one block (128 thr) per batch element. Only launched for t in [0,126].
__global__ __launch_bounds__(128) void stack_step(
    float* __restrict__ znext, const float* __restrict__ emb,
    const int* __restrict__ x,
    const float* __restrict__ Wpop, const float* __restrict__ bpop,
    const float* __restrict__ Wpush, const float* __restrict__ bpush,
    const float* __restrict__ Wval, const float* __restrict__ bval,
    float* __restrict__ s, float* __restrict__ V, int t) {
  const int b = blockIdx.x;
  const int tid = threadIdx.x;
  __shared__ float hb[HID];
  __shared__ float red[128];
  __shared__ float vals[128];
  __shared__ float ss[128];
  float* zb = znext + b * KZ;
  for (int k = tid; k < HID; k += 128) hb[k] = zb[EMB + STK + k];
  __syncthreads();
  // pop & push logits (512-dot, block reduce)
  float p0 = 0.f, p1 = 0.f;
  for (int k = tid; k < HID; k += 128) {
    p0 = fmaf(hb[k], Wpop[k], p0);
    p1 = fmaf(hb[k], Wpush[k], p1);
  }
  red[tid] = p0; __syncthreads();
  for (int off = 64; off > 0; off >>= 1) { if (tid < off) red[tid] += red[tid + off]; __syncthreads(); }
  const float pop = 1.f / (1.f + expf(-(red[0] + bpop[0])));
  __syncthreads();
  red[tid] = p1; __syncthreads();
  for (int off = 64; off > 0; off >>= 1) { if (tid < off) red[tid] += red[tid + off]; __syncthreads(); }
  const float push = 1.f / (1.f + expf(-(red[0] + bpush[0])));
  __syncthreads();
  // vals = relu(W_val @ h + b_val) : thread v owns one output row
  float va = 0.f;
  const float* wrow = Wval + tid * HID;
  for (int k = 0; k < HID; k += 4) {
    float4 w4 = *(const float4*)&wrow[k];
    va = fmaf(hb[k + 0], w4.x, va);
    va = fmaf(hb[k + 1], w4.y, va);
    va = fmaf(hb[k + 2], w4.z, va);
    va = fmaf(hb[k + 3], w4.w, va);
  }
  va = fmaxf(va + bval[tid], 0.f);
  vals[tid] = va;
  // strengths update: suf_i = sum_{k>i} s_k  via inclusive scan
  const float sv = s[b * TLEN + tid];
  ss[tid] = sv; __syncthreads();
  for (int off = 1; off < 128; off <<= 1) {
    float add = (tid >= off) ? ss[tid - off] : 0.f;
    __syncthreads();
    ss[tid] += add;
    __syncthreads();
  }
  const float suf = ss[127] - ss[tid];
  float nsv = fmaxf(sv - fmaxf(pop - suf, 0.f), 0.f);
  if (tid == t) nsv = push;
  __syncthreads();
  ss[tid] = nsv; __syncthreads();
  for (int off = 1; off < 128; off <<= 1) {
    float add = (tid >= off) ? ss[tid - off] : 0.f;
    __syncthreads();
    ss[tid] += add;
    __syncthreads();
  }
  const float suf2 = ss[127] - ss[tid];
  const float wv = fminf(nsv, fmaxf(1.f - suf2, 0.f));
  s[b * TLEN + tid] = nsv;
  V[((size_t)b * TLEN + t) * STK + tid] = va;
  __syncthreads();
  red[tid] = wv;   // reuse as w[] broadcast buffer
  __syncthreads();
  // r = sum_i w_i * V[b,i,:]  (rows i>t have w==0 exactly; row t taken from LDS)
  float racc = 0.f;
  const float* Vb = V + (size_t)b * TLEN * STK;
  for (int i = 0; i < TLEN; ++i) {
    float vi = (i == t) ? vals[tid] : Vb[i * STK + tid];
    racc = fmaf(red[i], vi, racc);
  }
  zb[EMB + tid] = racc;                       // r into next z
  int xv = x[(t + 1) * BSZ + b];
  zb[tid] = emb[xv * EMB + tid];              // next token embedding into next z
}

// ---------------- epilogue: sigmoid( relu(h@W_out^T+b_out) @ W_cls^T + b_cls ) ----------------
// grid(157 vgroups, 4 bgroups); tile [32 b x 32 vocab]; fused W_cls dot, atomicAdd per b.
__global__ __launch_bounds__(256) void final_out(
    const float* __restrict__ zfin, const float* __restrict__ Wout,
    const float* __restrict__ bout, const float* __restrict__ Wcls,
    float* __restrict__ accb) {
  __shared__ float HT[32][65];
  __shared__ float WTt[64][36];
  __shared__ float red2[32][8];
  const int cg = blockIdx.x;
  const int bg = blockIdx.y;
  const int tid = threadIdx.x;
  const int bl = tid >> 3;
  const int ul = tid & 7;
  const int r  = tid >> 3;
  const int ci = (tid & 7) * 8;
  float a0 = 0.f, a1 = 0.f, a2 = 0.f, a3 = 0.f;
  for (int kc = 0; kc < HID; kc += 64) {
    float4 ha  = *(const float4*)&zfin[(bg * 32 + r) * KZ + (EMB + STK) + kc + ci];
    float4 hb4 = *(const float4*)&zfin[(bg * 32 + r) * KZ + (EMB + STK) + kc + ci + 4];
    int vrow = cg * 32 + r;
    float4 wa = make_float4(0.f, 0.f, 0.f, 0.f), wb = make_float4(0.f, 0.f, 0.f, 0.f);
    if (vrow < VOCAB) {
      wa = *(const float4*)&Wout[vrow * HID + kc + ci];
      wb = *(const float4*)&Wout[vrow * HID + kc + ci + 4];
    }
    HT[r][ci + 0] = ha.x;  HT[r][ci + 1] = ha.y;  HT[r][ci + 2] = ha.z;  HT[r][ci + 3] = ha.w;
    HT[r][ci + 4] = hb4.x; HT[r][ci + 5] = hb4.y; HT[r][ci + 6] = hb4.z; HT[r][ci + 7] = hb4.w;
    WTt[ci + 0][r] = wa.x; WTt[ci + 1][r] = wa.y; WTt[ci + 2][r] = wa.z; WTt[ci + 3][r] = wa.w;
    WTt[ci + 4][r] = wb.x; WTt[ci + 5][r] = wb.y; WTt[ci + 6][r] = wb.z; WTt[ci + 7][r] = wb.w;
    __syncthreads();
#pragma unroll 16
    for (int k = 0; k < 64; ++k) {
      float hv = HT[bl][k];
      float4 wv = *(const float4*)&WTt[k][ul * 4];
      a0 = fmaf(hv, wv.x, a0);
      a1 = fmaf(hv, wv.y, a1);
      a2 = fmaf(hv, wv.z, a2);
      a3 = fmaf(hv, wv.w, a3);
    }
    __syncthreads();
  }
  const int v0 = cg * 32 + ul * 4;
  float part = 0.f;
  if (v0 + 0 < VOCAB) part = fmaf(fmaxf(a0 + bout[v0 + 0], 0.f), Wcls[v0 + 0], part);
  if (v0 + 1 < VOCAB) part = fmaf(fmaxf(a1 + bout[v0 + 1], 0.f), Wcls[v0 + 1], part);
  if (v0 + 2 < VOCAB) part = fmaf(fmaxf(a2 + bout[v0 + 2], 0.f), Wcls[v0 + 2], part);
  if (v0 + 3 < VOCAB) part = fmaf(fmaxf(a3 + bout[v0 + 3], 0.f), Wcls[v0 + 3], part);
  red2[bl][ul] = part;
  __syncthreads();
  if (tid < 32) {
    float sum = 0.f;
#pragma unroll
    for (int q = 0; q < 8; ++q) sum += red2[tid][q];
    atomicAdd(&accb[bg * 32 + tid], sum);
  }
}

__global__ __launch_bounds__(128) void final_sig(
    const float* __restrict__ accb, const float* __restrict__ bcls,
    float* __restrict__ out) {
  int b = threadIdx.x;
  out[b] = 1.f / (1.f + expf(-(accb[b] + bcls[0])));
}

extern "C" void kernel_launch(void* const* d_in, const int* in_sizes, int n_in,
                              void* d_out, int out_size, void* d_ws, size_t ws_size,
                              hipStream_t stream) {
  const int*   x      = (const int*)d_in[0];
  const float* emb    = (const float*)d_in[1];
  const float* W_ih   = (const float*)d_in[2];
  const float* b_ih   = (const float*)d_in[3];
  const float* W_hh   = (const float*)d_in[4];
  const float* b_hh   = (const float*)d_in[5];
  const float* W_out  = (const float*)d_in[6];
  const float* b_out  = (const float*)d_in[7];
  const float* W_push = (const float*)d_in[8];
  const float* b_push = (const float*)d_in[9];
  const float* W_pop  = (const float*)d_in[10];
  const float* b_pop  = (const float*)d_in[11];
  const float* W_val  = (const float*)d_in[12];
  const float* b_val  = (const float*)d_in[13];
  const float* W_cls  = (const float*)d_in[14];
  const float* b_cls  = (const float*)d_in[15];

  float* ws   = (float*)d_ws;
  float* Wc   = ws;                         // 2048*768 = 1,572,864
  float* bc   = Wc + NG * KZ;               // 2048
  float* z0   = bc + NG;                    // 128*768
  float* z1   = z0 + BSZ * KZ;              // 128*768
  float* c    = z1 + BSZ * KZ;              // 128*512
  float* s    = c + BSZ * HID;              // 128*128
  float* V    = s + BSZ * TLEN;             // 128*128*128
  float* accb = V + (size_t)BSZ * TLEN * STK; // 128
  float* zbuf[2] = { z0, z1 };

  build_wc<<<(NG * KZ + 255) / 256, 256, 0, stream>>>(W_ih, W_hh, b_ih, b_hh, Wc, bc);
  {
    int total = BSZ * KZ + BSZ * HID + BSZ * TLEN + BSZ;
    init_state<<<(total + 255) / 256, 256, 0, stream>>>(x, emb, z0, c, s, accb);
  }
  for (int t = 0; t < TLEN; ++t) {
    gates_cell<<<dim3(64, 4), 256, 0, stream>>>(zbuf[t & 1], zbuf[(t + 1) & 1], Wc, bc, c);
    if (t < TLEN - 1)
      stack_step<<<BSZ, 128, 0, stream>>>(zbuf[(t + 1) & 1], emb, x,
                                          W_pop, b_pop, W_push, b_push,
                                          W_val, b_val, s, V, t);
  }
  // final h lives in zbuf[TLEN & 1] == z0, cols [256:768)
  final_out<<<dim3((VOCAB + 31) / 32, 4), 256, 0, stream>>>(z0, W_out, b_out, W_cls, accb);
  final_sig<<<1, 128, 0, stream>>>(accb, b_cls, (float*)d_out);
}